// Round 5
// baseline (133.900 us; speedup 1.0000x reference)
//
#include <hip/hip_runtime.h>
#include <math.h>

#define PI_D 3.14159265358979323846
#define PIF  3.14159265358979323846f
#define NLAT 128
#define NLON 256
#define LMAX 50
#define MMAX 50
#define NPTS 2048
#define NBT 16
#define NBA 32
#define NBIN (NBT * NBA)
#define WBIN 0.19634954084936207f   /* pi/16 */
#define INVW 5.092958178940651f     /* 16/pi */
#define BIG 1e30f
#define KMASK 0xFFFFF800u           /* high 21 bits of distance, low 11 = index */
#define NBLK 256
#define NGRP 8                      /* 32 blocks per barrier group */

// Scratch in device globals (workspace poison fill is unconditional; d_ws gives
// no benefit). All data arrays fully rewritten before any read, every launch.
__device__ float2 g_btl[4][NPTS];                       // binned (theta,az)
__device__ float  g_br[4][NPTS];                        // binned radius
__device__ int    g_boff[4][NBIN + 1];                  // bin offsets
__device__ float  g_pctwT[(size_t)LMAX * NLAT * MMAX];  // 1.28 MB
__device__ float  g_fre[(size_t)4 * NLAT * MMAX];       // 100 KB

// Monotonic hierarchical grid-barrier state. NEVER reset: counters only grow;
// each launch derives its epoch from an entry-time read (launches are
// stream-serialized, and root < (epoch+1)*NGRP until the LAST block arrives,
// so any pre-arrival read yields the current epoch). 128B padding per counter.
__device__ int g_grp[2][NGRP][32];
__device__ int g_root[2][32];

__device__ __forceinline__ void gb_arrive_wait(int phase, int bid, int target) {
    int g = bid >> 5;                                   // 8 groups of 32
    int prev = __hip_atomic_fetch_add(&g_grp[phase][g][0], 1,
                   __ATOMIC_RELAXED, __HIP_MEMORY_SCOPE_AGENT);
    if ((prev & 31) == 31) {                            // last of group (any epoch)
        __hip_atomic_fetch_add(&g_root[phase][0], 1,
                   __ATOMIC_RELAXED, __HIP_MEMORY_SCOPE_AGENT);
    }
    while (__hip_atomic_load(&g_root[phase][0],
                   __ATOMIC_RELAXED, __HIP_MEMORY_SCOPE_AGENT) < target) {
        __builtin_amdgcn_s_sleep(32);                   // ~0.85us poll backoff
    }
}

__device__ __forceinline__ void insert3(float kf, float& k0, float& k1, float& k2) {
    float n1 = __builtin_amdgcn_fmed3f(kf, k0, k1);
    float n2 = __builtin_amdgcn_fmed3f(kf, k1, k2);
    k0 = fminf(kf, k0);
    k1 = n1;
    k2 = n2;
}

__device__ __forceinline__ float mkkey(float gt, float gl, float2 tl, int idx) {
    float dt = gt - tl.x, dl = gl - tl.y;
    float d = fmaf(dt, dt, dl * dl);
    return __uint_as_float((__float_as_uint(d) & KMASK) | (unsigned)idx);
}

// Full 3-NN query + interpolation for one (lat, lon). Identical fp op order to
// the round-0/1 passing kernel. lat is block-uniform (wave-vote safe).
__device__ __forceinline__ float query_row(const float2* __restrict__ btl,
                                           const float* __restrict__ br,
                                           const int* s_off, int lat, int j) {
    float gt = (float)((double)lat * PI_D / 128.0);
    float gl = (float)(((double)j - 128.0) * PI_D / 128.0);
    float glp = gl + PIF;
    int bt0 = lat >> 3;
    int ba0 = j >> 3;

    auto scan_seg = [&](int i, int i1, float& q0, float& q1, float& q2) {
        for (; i + 4 <= i1; i += 4) {
            float2 a0 = btl[i];
            float2 a1 = btl[i + 1];
            float2 a2 = btl[i + 2];
            float2 a3 = btl[i + 3];
            insert3(mkkey(gt, gl, a0, i), q0, q1, q2);
            insert3(mkkey(gt, gl, a1, i + 1), q0, q1, q2);
            insert3(mkkey(gt, gl, a2, i + 2), q0, q1, q2);
            insert3(mkkey(gt, gl, a3, i + 3), q0, q1, q2);
        }
        for (; i < i1; ++i)
            insert3(mkkey(gt, gl, btl[i], i), q0, q1, q2);
    };

    float k0 = BIG, k1 = BIG, k2 = BIG;
    {
        int rtl = max(bt0 - 1, 0), rth = min(bt0 + 1, NBT - 1);
        int bal = max(ba0 - 1, 0), bah = min(ba0 + 1, NBA - 1);
        for (int bt = rtl; bt <= rth; ++bt)
            scan_seg(s_off[bt * NBA + bal], s_off[bt * NBA + bah + 1], k0, k1, k2);
    }

    bool done;
    {
        float safe = BIG;
        if (bt0 - 1 > 0)       safe = fminf(safe, gt - (float)(bt0 - 1) * WBIN);
        if (bt0 + 1 < NBT - 1) safe = fminf(safe, (float)(bt0 + 2) * WBIN - gt);
        if (ba0 - 1 > 0)       safe = fminf(safe, glp - (float)(ba0 - 1) * WBIN);
        if (ba0 + 1 < NBA - 1) safe = fminf(safe, (float)(ba0 + 2) * WBIN - glp);
        done = (k2 <= safe * safe);
    }

    for (int R = 2; R <= 31; ++R) {
        if (__all(done)) break;
        if (!done) {
            int btl_ = bt0 - R, bth = bt0 + R;
            int lo = max(btl_, 0), hi = min(bth, NBT - 1);
            int bal = max(ba0 - R, 0), bah = min(ba0 + R, NBA - 1);
            for (int bt = lo; bt <= hi; ++bt) {
                if (bt == btl_ || bt == bth) {
                    scan_seg(s_off[bt * NBA + bal], s_off[bt * NBA + bah + 1], k0, k1, k2);
                } else {
                    if (ba0 - R >= 0) {
                        int b = bt * NBA + ba0 - R;
                        scan_seg(s_off[b], s_off[b + 1], k0, k1, k2);
                    }
                    if (ba0 + R <= NBA - 1) {
                        int b = bt * NBA + ba0 + R;
                        scan_seg(s_off[b], s_off[b + 1], k0, k1, k2);
                    }
                }
            }
            float safe = BIG;
            if (bt0 - R > 0)       safe = fminf(safe, gt - (float)(bt0 - R) * WBIN);
            if (bt0 + R < NBT - 1) safe = fminf(safe, (float)(bt0 + R + 1) * WBIN - gt);
            if (ba0 - R > 0)       safe = fminf(safe, glp - (float)(ba0 - R) * WBIN);
            if (ba0 + R < NBA - 1) safe = fminf(safe, (float)(ba0 + R + 1) * WBIN - glp);
            if (k2 <= safe * safe) done = true;
        }
    }

    int i0 = __float_as_uint(k0) & 0x7FF;
    int i1 = __float_as_uint(k1) & 0x7FF;
    int i2 = __float_as_uint(k2) & 0x7FF;
    float2 p0 = btl[i0];
    float2 p1 = btl[i1];
    float2 p2 = btl[i2];
    float dt0 = gt - p0.x, dl0 = gl - p0.y;
    float dt1 = gt - p1.x, dl1 = gl - p1.y;
    float dt2 = gt - p2.x, dl2 = gl - p2.y;
    float d0 = fmaf(dt0, dt0, dl0 * dl0);
    float d1 = fmaf(dt1, dt1, dl1 * dl1);
    float d2 = fmaf(dt2, dt2, dl2 * dl2);
    float s = d0 + d1 + d2;
    return (d0 * br[i0] + d1 * br[i1] + d2 * br[i2]) / s;
}

// DFT partials for one row (verbatim fp order).
__device__ __forceinline__ void dft_row(const float* row, float* part, int t) {
    int q = t >> 6;        // quarter 0..3
    int mm = t & 63;       // mode
    if (mm < MMAX) {
        int bs = q * 64;
        const float W0 = 2.0f * PIF / 256.0f;
        float cphi2 = 2.0f * __cosf(W0 * (float)mm);
        float acc = 0.0f;
#pragma unroll
        for (int seg = 0; seg < 4; ++seg) {
            int i0 = bs + seg * 16;
            float c0 = __cosf(W0 * (float)((i0 * mm) & 255));
            float c1 = __cosf(W0 * (float)(((i0 + 1) * mm) & 255));
            acc = fmaf(row[i0], c0, acc);
            acc = fmaf(row[i0 + 1], c1, acc);
#pragma unroll
            for (int i = 2; i < 16; ++i) {
                float cn = fmaf(cphi2, c1, -c0);
                acc = fmaf(row[i0 + i], cn, acc);
                c0 = c1;
                c1 = cn;
            }
        }
        part[q * 64 + mm] = acc;
    }
}

// PCTW column (k, m): verbatim fp order.
__device__ __forceinline__ void pctw_col(int k, int m) {
    double thd = PI_D * (double)k / 127.0;
    float cost = (float)cos(thd);
    float sint = (float)sin(thd);           // >= 0 on [0,pi]

    float c2 = (float)cos(2.0 * thd);
    float two_c2 = 2.0f * c2;
    float cp = 1.0f, cc = c2, v = 0.0f;
    for (int tt = 1; tt <= 63; ++tt) {
        v += 2.0f * cc / (float)(4 * tt * tt - 1);
        float cn = two_c2 * cc - cp;
        cp = cc;
        cc = cn;
    }
    float w = (2.0f / 127.0f) * (1.0f - v);
    if (k == 0 || k == 127) w *= 0.5f;

    float pmm = sqrtf(1.0f / (4.0f * PIF));
    for (int i = 1; i <= m; ++i)
        pmm = -pmm * sqrtf((2.0f * (float)i + 1.0f) / (2.0f * (float)i)) * sint;

    float* o = g_pctwT + (size_t)k * MMAX + m;   // pctwT[(l*NLAT+k)*MMAX+m]
    for (int l = 0; l < m; ++l) o[(size_t)l * NLAT * MMAX] = 0.0f;
    o[(size_t)m * NLAT * MMAX] = pmm * w;
    float plm2 = pmm, plm1 = 0.0f;
    if (m + 1 < LMAX) {
        plm1 = sqrtf(2.0f * (float)m + 3.0f) * cost * pmm;
        o[(size_t)(m + 1) * NLAT * MMAX] = plm1 * w;
    }
    for (int l = m + 2; l < LMAX; ++l) {
        float fl = (float)l;
        float denom = fl * fl - (float)(m * m);          // exact (<2^24)
        float a = sqrtf((4.0f * fl * fl - 1.0f) / denom);
        float b = sqrtf(((2.0f * fl + 1.0f) * (float)(l - 1 + m) * (float)(l - 1 - m)) /
                        ((2.0f * fl - 3.0f) * denom));
        float p = a * cost * plm1 - b * plm2;
        o[(size_t)l * NLAT * MMAX] = p * w;
        plm2 = plm1;
        plm1 = p;
    }
}

// ---------------------------------------------------------------------------
// ONE kernel, 256 blocks x 256 threads = exactly 1 block/CU (co-residency
// guaranteed -> grid barrier deadlock-proof).
//   Phase 0: blocks 0..3 bin field bid into global; block 0 zeroes out[0].
//   [barrier A]
//   Phase 1: every block: 3-NN query + interp + DFT for TWO adjacent lat rows
//            (f = bid>>6, lats 2*(bid&63), +1) + a 25-task PCTW share
//            (k = bid>>1, m = (bid&1)*25 + t).
//   [barrier B]
//   Phase 2: blocks 0..99 contract tile (b,l) + loss atomic.
// ---------------------------------------------------------------------------
__global__ __launch_bounds__(256) void fused_one(
    const float* __restrict__ pred, const float* __restrict__ tgt,
    float* __restrict__ out) {

    __shared__ int   s_cnt[NBIN];         // binning counts/cursor       2 KB
    __shared__ int   s_off[NBIN + 1];     // bin offsets                 2 KB
    __shared__ float s_row[2][NLON];      // interp rows                 2 KB
    __shared__ float s_part[256];         // DFT partials                1 KB
    __shared__ float sp[4][64], st_[4][64]; // contract partials         2 KB

    int bid = blockIdx.x;
    int t = threadIdx.x;

    // Entry-time epoch reads (pre-arrival => still epoch N; see g_root note).
    int tgtA = 0, tgtB = 0;
    if (t == 0) {
        int e0 = __hip_atomic_load(&g_root[0][0], __ATOMIC_RELAXED, __HIP_MEMORY_SCOPE_AGENT);
        int e1 = __hip_atomic_load(&g_root[1][0], __ATOMIC_RELAXED, __HIP_MEMORY_SCOPE_AGENT);
        tgtA = (e0 & ~(NGRP - 1)) + NGRP;
        tgtB = (e1 & ~(NGRP - 1)) + NGRP;
    }

    // ======================= PHASE 0: bin fields ============================
    if (bid < 4) {
        int f = bid;
        const float* src = ((f < 2) ? pred : tgt) + (size_t)(f & 1) * NPTS * 3;
        if (bid == 0 && t == 0) out[0] = 0.0f;

        for (int i = t; i < NBIN; i += 256) s_cnt[i] = 0;
        __syncthreads();

        float pth[8], paz[8], pr[8];
        int pbin[8];
#pragma unroll
        for (int i = 0; i < 8; ++i) {
            int n = t + 256 * i;
            float x = src[3 * n], y = src[3 * n + 1], z = src[3 * n + 2];
            float s1 = z * z;
            float s2 = s1 + y * y;
            float s3 = s2 + x * x;
            float r = sqrtf(s3);
            float rho = sqrtf(s2);
            float th = acosf(x / r);
            float a = acosf(y / rho);
            float az = (z < 0.0f) ? (a + (2.0f * PIF - 2.0f * a)) : a;
            az -= PIF;
            int bt = min(max((int)(th * INVW), 0), NBT - 1);
            int ba = min(max((int)((az + PIF) * INVW), 0), NBA - 1);
            int b = bt * NBA + ba;
            pth[i] = th; paz[i] = az; pr[i] = r; pbin[i] = b;
            atomicAdd(&s_cnt[b], 1);
        }
        __syncthreads();

        if (t == 0) s_off[NBIN] = NPTS;
        if (t < 64) {
            int base = t * 8;
            int loc[8];
            int run = 0;
#pragma unroll
            for (int i = 0; i < 8; ++i) { loc[i] = run; run += s_cnt[base + i]; }
            int x = run;
#pragma unroll
            for (int d = 1; d < 64; d <<= 1) {
                int y = __shfl_up(x, d);
                if (t >= d) x += y;
            }
            int ex = x - run;
#pragma unroll
            for (int i = 0; i < 8; ++i) s_off[base + i] = ex + loc[i];
        }
        __syncthreads();
        for (int i = t; i < NBIN; i += 256) s_cnt[i] = s_off[i];
        for (int i = t; i <= NBIN; i += 256) g_boff[f][i] = s_off[i];
        __syncthreads();
#pragma unroll
        for (int i = 0; i < 8; ++i) {
            int pos = atomicAdd(&s_cnt[pbin[i]], 1);
            g_btl[f][pos] = make_float2(pth[i], paz[i]);
            g_br[f][pos] = pr[i];
        }
    }

    // ======================= BARRIER A =====================================
    __syncthreads();
    if (t == 0) { __threadfence(); gb_arrive_wait(0, bid, tgtA); }
    __syncthreads();
    __threadfence();

    // ======================= PHASE 1: query 2 rows + DFT + PCTW ============
    {
        int f = bid >> 6;                 // 0..3
        int lat0 = (bid & 63) * 2;        // even lat; lat0,lat0+1 share bt0
        const float2* __restrict__ btl = g_btl[f];
        const float*  __restrict__ br  = g_br[f];

        for (int i = t; i <= NBIN; i += 256) s_off[i] = g_boff[f][i];
        __syncthreads();

        s_row[0][t] = query_row(btl, br, s_off, lat0, t);
        s_row[1][t] = query_row(btl, br, s_off, lat0 + 1, t);
        __syncthreads();

        dft_row(s_row[0], s_part, t);
        __syncthreads();
        if (t < MMAX)
            g_fre[(f * NLAT + lat0) * MMAX + t] =
                ((s_part[t] + s_part[64 + t]) + (s_part[128 + t] + s_part[192 + t])) *
                (float)(2.0 * PI_D / (double)NLON);
        __syncthreads();
        dft_row(s_row[1], s_part, t);
        __syncthreads();
        if (t < MMAX)
            g_fre[(f * NLAT + lat0 + 1) * MMAX + t] =
                ((s_part[t] + s_part[64 + t]) + (s_part[128 + t] + s_part[192 + t])) *
                (float)(2.0 * PI_D / (double)NLON);

        // PCTW share: 2 blocks per k-column, 25 m-values per block.
        if (t < 25) pctw_col(bid >> 1, (bid & 1) * 25 + t);
    }

    // ======================= BARRIER B =====================================
    __syncthreads();
    if (t == 0) { __threadfence(); gb_arrive_wait(1, bid, tgtB); }
    __syncthreads();
    __threadfence();

    // ======================= PHASE 2: contract + loss ======================
    if (bid < 2 * LMAX) {
        int b = bid / LMAX;
        int l = bid % LMAX;
        int mm = t & 63;
        int kq = t >> 6;
        float pc = 0.0f, tc = 0.0f;
        if (mm < MMAX) {
            const float* pw = g_pctwT + ((size_t)l * NLAT + kq * 32) * MMAX + mm;
            const float* fp = g_fre + ((size_t)b * NLAT + kq * 32) * MMAX + mm;
            const float* ft = g_fre + ((size_t)(2 + b) * NLAT + kq * 32) * MMAX + mm;
#pragma unroll 8
            for (int k = 0; k < 32; ++k) {
                float w = pw[k * MMAX];
                pc += fp[k * MMAX] * w;
                tc += ft[k * MMAX] * w;
            }
        }
        sp[kq][mm] = pc;
        st_[kq][mm] = tc;
        __syncthreads();
        if (t < 64) {
            int m2 = t;
            float pcs = (sp[0][m2] + sp[1][m2]) + (sp[2][m2] + sp[3][m2]);
            float tcs = (st_[0][m2] + st_[1][m2]) + (st_[2][m2] + st_[3][m2]);
            float diff = pcs - tcs;
            double dl_ = (double)(49 - l);
            float rw = (float)exp(-(dl_ * dl_) / 5000.0);
            float contrib = (m2 < MMAX) ? diff * diff * rw * 0.5f : 0.0f;
            for (int off = 32; off > 0; off >>= 1) contrib += __shfl_down(contrib, off);
            if (m2 == 0) atomicAdd(out, contrib);
        }
    }
}

// ---------------------------------------------------------------------------
extern "C" void kernel_launch(void* const* d_in, const int* in_sizes, int n_in,
                              void* d_out, int out_size, void* d_ws, size_t ws_size,
                              hipStream_t stream) {
    const float* pred = (const float*)d_in[0];
    const float* tgt = (const float*)d_in[1];
    float* out = (float*)d_out;
    (void)d_ws; (void)ws_size;  // workspace unused (poison fill is unconditional)

    fused_one<<<NBLK, 256, 0, stream>>>(pred, tgt, out);
}

// Round 7
// 78.677 us; speedup vs baseline: 1.7019x; 1.7019x over previous
//
#include <hip/hip_runtime.h>
#include <math.h>

#define PI_D 3.14159265358979323846
#define PIF  3.14159265358979323846f
#define NLAT 128
#define NLON 256
#define LMAX 50
#define MMAX 50
#define NPTS 2048
#define NBT 16
#define NBA 32
#define NBIN (NBT * NBA)
#define WBIN 0.19634954084936207f   /* pi/16 */
#define INVW 5.092958178940651f     /* 16/pi */
#define BIG 1e30f
#define KMASK 0xFFFFF800u           /* high 21 bits of distance, low 11 = index */

__device__ __forceinline__ void insert3(float kf, float& k0, float& k1, float& k2) {
    float n1 = __builtin_amdgcn_fmed3f(kf, k0, k1);
    float n2 = __builtin_amdgcn_fmed3f(kf, k1, k2);
    k0 = fminf(kf, k0);
    k1 = n1;
    k2 = n2;
}

__device__ __forceinline__ float mkkey(float gt, float gl, float2 tl, int idx) {
    float dt = gt - tl.x, dl = gl - tl.y;
    float d = fmaf(dt, dt, dl * dl);
    return __uint_as_float((__float_as_uint(d) & KMASK) | (unsigned)idx);
}

// ---------------------------------------------------------------------------
// Kernel 1 (fused), 256 blocks = 1 per CU, 1024 threads:
//   blocks 0..127   = binned knn + interp + DFT for FOUR lat rows (one field,
//                     lat-quad). Each thread: one (lon,lat) query + one DFT task.
//   blocks 128..255 = PCTW column k = bid-128, f32 (lane = m);
//                     block 128 zeroes out[0].
// ---------------------------------------------------------------------------
__global__ __launch_bounds__(1024) void fused_main(
    const float* __restrict__ pred, const float* __restrict__ tgt,
    float* __restrict__ pctwT, float* __restrict__ fre, float* __restrict__ out) {

    __shared__ float2 s_btl[NPTS];        // (theta, az) in bin order   16 KB
    __shared__ float  s_br[NPTS];         // radius in bin order         8 KB
    __shared__ int    s_cnt[NBIN];        // counts, then scatter cursor 2 KB
    __shared__ int    s_off[NBIN + 1];    // bin start offsets           2 KB
    __shared__ float  s_row[4][NLON];     // interp rows                 4 KB
    __shared__ float  s_part[4][256];     // DFT partials                4 KB

    int bid = blockIdx.x;
    int t = threadIdx.x;

    if (bid >= 128) {
        // ---------------- PCTW role, f32 (R10-validated) ----------------
        int k = bid - 128;                      // 0..127
        int m = t;
        if (k == 0 && m == 0) out[0] = 0.0f;    // init for contract's atomics
        if (m >= MMAX) return;

        double thd = PI_D * (double)k / 127.0;
        float cost = (float)cos(thd);
        float sint = (float)sin(thd);           // >= 0 on [0,pi]

        // Clenshaw-Curtis weight (Nn=127, odd), f32 Chebyshev recurrence
        float c2 = (float)cos(2.0 * thd);
        float two_c2 = 2.0f * c2;
        float cp = 1.0f, cc = c2, v = 0.0f;
        for (int tt = 1; tt <= 63; ++tt) {
            v += 2.0f * cc / (float)(4 * tt * tt - 1);
            float cn = two_c2 * cc - cp;
            cp = cc;
            cc = cn;
        }
        float w = (2.0f / 127.0f) * (1.0f - v);
        if (k == 0 || k == 127) w *= 0.5f;

        float pmm = sqrtf(1.0f / (4.0f * PIF));
        for (int i = 1; i <= m; ++i)
            pmm = -pmm * sqrtf((2.0f * (float)i + 1.0f) / (2.0f * (float)i)) * sint;

        float* o = pctwT + (size_t)k * MMAX + m;   // pctwT[(l*NLAT+k)*MMAX+m]
        for (int l = 0; l < m; ++l) o[(size_t)l * NLAT * MMAX] = 0.0f;
        o[(size_t)m * NLAT * MMAX] = pmm * w;
        float plm2 = pmm, plm1 = 0.0f;
        if (m + 1 < LMAX) {
            plm1 = sqrtf(2.0f * (float)m + 3.0f) * cost * pmm;
            o[(size_t)(m + 1) * NLAT * MMAX] = plm1 * w;
        }
        for (int l = m + 2; l < LMAX; ++l) {
            float fl = (float)l;
            float denom = fl * fl - (float)(m * m);          // exact (<2^24)
            float a = sqrtf((4.0f * fl * fl - 1.0f) / denom);
            float b = sqrtf(((2.0f * fl + 1.0f) * (float)(l - 1 + m) * (float)(l - 1 - m)) /
                            ((2.0f * fl - 3.0f) * denom));
            float p = a * cost * plm1 - b * plm2;
            o[(size_t)l * NLAT * MMAX] = p * w;
            plm2 = plm1;
            plm1 = p;
        }
        return;
    }

    // ---------------- KNN role: bin once, query FOUR lat rows ----------------
    int f = bid >> 5;            // 0..3
    int lat0 = (bid & 31) * 4;   // first lat row of the quad
    const float* src = ((f < 2) ? pred : tgt) + (size_t)(f & 1) * NPTS * 3;

    if (t < NBIN) s_cnt[t] = 0;
    __syncthreads();

    // to_spherical into registers (exact reference fp order) + bin counts
    float pth[2], paz[2], pr[2];
    int pbin[2];
#pragma unroll
    for (int i = 0; i < 2; ++i) {
        int n = t + 1024 * i;
        float x = src[3 * n], y = src[3 * n + 1], z = src[3 * n + 2];
        float s1 = z * z;
        float s2 = s1 + y * y;
        float s3 = s2 + x * x;
        float r = sqrtf(s3);
        float rho = sqrtf(s2);
        float th = acosf(x / r);
        float a = acosf(y / rho);
        float az = (z < 0.0f) ? (a + (2.0f * PIF - 2.0f * a)) : a;
        az -= PIF;
        int bt = min(max((int)(th * INVW), 0), NBT - 1);
        int ba = min(max((int)((az + PIF) * INVW), 0), NBA - 1);
        int b = bt * NBA + ba;
        pth[i] = th; paz[i] = az; pr[i] = r; pbin[i] = b;
        atomicAdd(&s_cnt[b], 1);
    }
    __syncthreads();

    // exclusive scan of 512 counts by one wave (8 bins per lane)
    if (t == 0) s_off[NBIN] = NPTS;
    if (t < 64) {
        int base = t * 8;
        int loc[8];
        int run = 0;
#pragma unroll
        for (int i = 0; i < 8; ++i) { loc[i] = run; run += s_cnt[base + i]; }
        int x = run;
#pragma unroll
        for (int d = 1; d < 64; d <<= 1) {
            int y = __shfl_up(x, d);
            if (t >= d) x += y;
        }
        int ex = x - run;
#pragma unroll
        for (int i = 0; i < 8; ++i) s_off[base + i] = ex + loc[i];
    }
    __syncthreads();
    if (t < NBIN) s_cnt[t] = s_off[t];
    __syncthreads();
#pragma unroll
    for (int i = 0; i < 2; ++i) {
        int pos = atomicAdd(&s_cnt[pbin[i]], 1);
        s_btl[pos] = make_float2(pth[i], paz[i]);
        s_br[pos] = pr[i];
    }
    __syncthreads();

    // ---- 3-NN query: one (lon, lat) per thread; rl is wave-uniform ----
    int rl = t >> 8;            // 0..3, uniform within a wave
    int j = t & 255;            // lon
    int lat = lat0 + rl;
    float gt = (float)((double)lat * PI_D / 128.0);
    float gl = (float)(((double)j - 128.0) * PI_D / 128.0);
    float glp = gl + PIF;
    int bt0 = lat >> 3;         // wave-uniform
    int ba0 = j >> 3;

    auto scan_seg = [&](int i, int i1, float& q0, float& q1, float& q2) {
        for (; i + 4 <= i1; i += 4) {
            float2 a0 = s_btl[i];
            float2 a1 = s_btl[i + 1];
            float2 a2 = s_btl[i + 2];
            float2 a3 = s_btl[i + 3];
            insert3(mkkey(gt, gl, a0, i), q0, q1, q2);
            insert3(mkkey(gt, gl, a1, i + 1), q0, q1, q2);
            insert3(mkkey(gt, gl, a2, i + 2), q0, q1, q2);
            insert3(mkkey(gt, gl, a3, i + 3), q0, q1, q2);
        }
        for (; i < i1; ++i)
            insert3(mkkey(gt, gl, s_btl[i], i), q0, q1, q2);
    };

    float k0 = BIG, k1 = BIG, k2 = BIG;
    {
        int rtl = max(bt0 - 1, 0), rth = min(bt0 + 1, NBT - 1);
        int bal = max(ba0 - 1, 0), bah = min(ba0 + 1, NBA - 1);
        for (int bt = rtl; bt <= rth; ++bt)
            scan_seg(s_off[bt * NBA + bal], s_off[bt * NBA + bah + 1], k0, k1, k2);
    }

    bool done;
    {
        float safe = BIG;
        if (bt0 - 1 > 0)       safe = fminf(safe, gt - (float)(bt0 - 1) * WBIN);
        if (bt0 + 1 < NBT - 1) safe = fminf(safe, (float)(bt0 + 2) * WBIN - gt);
        if (ba0 - 1 > 0)       safe = fminf(safe, glp - (float)(ba0 - 1) * WBIN);
        if (ba0 + 1 < NBA - 1) safe = fminf(safe, (float)(ba0 + 2) * WBIN - glp);
        done = (k2 <= safe * safe);
    }

    // fallback: expanding rings R>=2 (R6/R12 verbatim)
    for (int R = 2; R <= 31; ++R) {
        if (__all(done)) break;
        if (!done) {
            int btl = bt0 - R, bth = bt0 + R;
            int lo = max(btl, 0), hi = min(bth, NBT - 1);
            int bal = max(ba0 - R, 0), bah = min(ba0 + R, NBA - 1);
            for (int bt = lo; bt <= hi; ++bt) {
                if (bt == btl || bt == bth) {
                    scan_seg(s_off[bt * NBA + bal], s_off[bt * NBA + bah + 1], k0, k1, k2);
                } else {
                    if (ba0 - R >= 0) {
                        int b = bt * NBA + ba0 - R;
                        scan_seg(s_off[b], s_off[b + 1], k0, k1, k2);
                    }
                    if (ba0 + R <= NBA - 1) {
                        int b = bt * NBA + ba0 + R;
                        scan_seg(s_off[b], s_off[b + 1], k0, k1, k2);
                    }
                }
            }
            float safe = BIG;
            if (bt0 - R > 0)       safe = fminf(safe, gt - (float)(bt0 - R) * WBIN);
            if (bt0 + R < NBT - 1) safe = fminf(safe, (float)(bt0 + R + 1) * WBIN - gt);
            if (ba0 - R > 0)       safe = fminf(safe, glp - (float)(ba0 - R) * WBIN);
            if (ba0 + R < NBA - 1) safe = fminf(safe, (float)(ba0 + R + 1) * WBIN - glp);
            if (k2 <= safe * safe) done = true;
        }
    }

    // epilogue: indices from keys, exact distances, interp weights
    {
        int i0 = __float_as_uint(k0) & 0x7FF;
        int i1 = __float_as_uint(k1) & 0x7FF;
        int i2 = __float_as_uint(k2) & 0x7FF;
        float2 p0 = s_btl[i0];
        float2 p1 = s_btl[i1];
        float2 p2 = s_btl[i2];
        float dt0 = gt - p0.x, dl0 = gl - p0.y;
        float dt1 = gt - p1.x, dl1 = gl - p1.y;
        float dt2 = gt - p2.x, dl2 = gl - p2.y;
        float d0 = fmaf(dt0, dt0, dl0 * dl0);
        float d1 = fmaf(dt1, dt1, dl1 * dl1);
        float d2 = fmaf(dt2, dt2, dl2 * dl2);
        float s = d0 + d1 + d2;
        s_row[rl][j] = (d0 * s_br[i0] + d1 * s_br[i1] + d2 * s_br[i2]) / s;
    }
    __syncthreads();

    // DFT: one (row, quarter, mode) task per thread. Row reads wave-uniform
    // broadcasts; cosines via Chebyshev recurrence re-seeded every 16 steps
    // (exact integer-mod angle reduction) -- zero LDS gathers.
    {
        int q = (t >> 6) & 3;  // quarter
        int mm = t & 63;       // mode
        if (mm < MMAX) {
            int bs = q * 64;
            const float W0 = 2.0f * PIF / 256.0f;
            float cphi2 = 2.0f * __cosf(W0 * (float)mm);
            float acc = 0.0f;
#pragma unroll
            for (int seg = 0; seg < 4; ++seg) {
                int i0 = bs + seg * 16;
                float c0 = __cosf(W0 * (float)((i0 * mm) & 255));
                float c1 = __cosf(W0 * (float)(((i0 + 1) * mm) & 255));
                acc = fmaf(s_row[rl][i0], c0, acc);
                acc = fmaf(s_row[rl][i0 + 1], c1, acc);
#pragma unroll
                for (int i = 2; i < 16; ++i) {
                    float cn = fmaf(cphi2, c1, -c0);
                    acc = fmaf(s_row[rl][i0 + i], cn, acc);
                    c0 = c1;
                    c1 = cn;
                }
            }
            s_part[rl][q * 64 + mm] = acc;
        }
    }
    __syncthreads();
    {
        int mm = t & 255;
        if (mm < MMAX) {
            const float* pp = s_part[rl];
            float v = ((pp[mm] + pp[64 + mm]) + (pp[128 + mm] + pp[192 + mm])) *
                      (float)(2.0 * PI_D / (double)NLON);
            fre[(f * NLAT + lat0 + rl) * MMAX + mm] = v;
        }
    }
}

// ---------------------------------------------------------------------------
// Kernel 2: Legendre contraction + loss (R10 verbatim). Block per (b,l);
// 256 threads = (mm 0..63) x (k-quarter 0..3); LDS reduce; one atomic/block.
// ---------------------------------------------------------------------------
__global__ __launch_bounds__(256) void contract_loss(const float* __restrict__ fre,
                                                     const float* __restrict__ pctwT,
                                                     float* __restrict__ out) {
    int b = blockIdx.x / LMAX;
    int l = blockIdx.x % LMAX;
    int mm = threadIdx.x & 63;
    int kq = threadIdx.x >> 6;
    __shared__ float sp[4][64], st_[4][64];
    float pc = 0.0f, tc = 0.0f;
    if (mm < MMAX) {
        const float* pw = pctwT + ((size_t)l * NLAT + kq * 32) * MMAX + mm;
        const float* fp = fre + ((size_t)b * NLAT + kq * 32) * MMAX + mm;
        const float* ft = fre + ((size_t)(2 + b) * NLAT + kq * 32) * MMAX + mm;
#pragma unroll 8
        for (int k = 0; k < 32; ++k) {
            float w = pw[k * MMAX];
            pc += fp[k * MMAX] * w;
            tc += ft[k * MMAX] * w;
        }
    }
    sp[kq][mm] = pc;
    st_[kq][mm] = tc;
    __syncthreads();
    if (threadIdx.x < 64) {
        int m2 = threadIdx.x;
        float pcs = (sp[0][m2] + sp[1][m2]) + (sp[2][m2] + sp[3][m2]);
        float tcs = (st_[0][m2] + st_[1][m2]) + (st_[2][m2] + st_[3][m2]);
        float diff = pcs - tcs;
        double dl_ = (double)(49 - l);
        float rw = (float)exp(-(dl_ * dl_) / 5000.0);
        float contrib = (m2 < MMAX) ? diff * diff * rw * 0.5f : 0.0f;
        for (int off = 32; off > 0; off >>= 1) contrib += __shfl_down(contrib, off);
        if (m2 == 0) atomicAdd(out, contrib);
    }
}

// ---------------------------------------------------------------------------
extern "C" void kernel_launch(void* const* d_in, const int* in_sizes, int n_in,
                              void* d_out, int out_size, void* d_ws, size_t ws_size,
                              hipStream_t stream) {
    const float* pred = (const float*)d_in[0];
    const float* tgt = (const float*)d_in[1];
    float* ws = (float*)d_ws;

    float* pctwT = ws;            // 50*128*50 = 320000 floats
    float* fre   = ws + 320000;   // 4*128*50  =  25600 floats
    float* out = (float*)d_out;

    fused_main<<<256, 1024, 0, stream>>>(pred, tgt, pctwT, fre, out);
    contract_loss<<<2 * LMAX, 256, 0, stream>>>(fre, pctwT, out);
}